// Round 5
// baseline (206.585 us; speedup 1.0000x reference)
//
#include <hip/hip_runtime.h>

#define B_N 32768
#define D 512
#define DD (D * D)
#define NLEV 10
#define TM 128
#define TN 256
#define BK 32
#define NITER (D / BK)            // 16
#define NHB 128                   // histogram blocks (B_N / 256)
#define MROWS_MAX 34048           // 32768 + 10*128 padding headroom
#define MAX_RT (MROWS_MAX / TM)   // 266
#define CSTR 260                  // epilogue LDS row stride (floats)

typedef unsigned short u16;
typedef short s16x8 __attribute__((ext_vector_type(8)));
typedef u16 u16x8 __attribute__((ext_vector_type(8)));
typedef float f32x4 __attribute__((ext_vector_type(4)));

__device__ __forceinline__ u16 f2bf(float f) {
  union { float f; unsigned u; } v; v.f = f;
  unsigned r = v.u + 0x7fffu + ((v.u >> 16) & 1u);  // RNE
  return (u16)(r >> 16);
}
__device__ __forceinline__ int clampv(int v) {
  return v < 0 ? 0 : (v > NLEV - 1 ? NLEV - 1 : v);
}

// ---- K1: weff-build (blocks 0..1023) UNION hist+perm-fill (blocks 1024..1151)
__global__ void k1(const float* __restrict__ W, const float* __restrict__ lg,
                   const float* __restrict__ attn, const int* __restrict__ val,
                   u16* __restrict__ weff, u16* __restrict__ hist,
                   int* __restrict__ perm) {
  const int t = threadIdx.x;
  if (blockIdx.x < DD / 256) {
    __shared__ float c[NLEV * NLEV];
    if (t < NLEV) {
      float g[NLEV], a[NLEV], mx = -1e30f;
      #pragma unroll
      for (int l = 0; l < NLEV; ++l) {
        g[l] = 1.0f / (1.0f + expf(-lg[l]));
        a[l] = attn[t * NLEV + l];
        mx = fmaxf(mx, a[l]);
      }
      float s = 0.f;
      #pragma unroll
      for (int l = 0; l < NLEV; ++l) { a[l] = expf(a[l] - mx); s += a[l]; }
      float inv = 1.0f / s;
      #pragma unroll
      for (int l = 0; l < NLEV; ++l) {
        float cc = 0.3f * a[l] * inv * g[l];
        if (l == t) cc += 0.7f * g[t];
        c[t * NLEV + l] = cc;
      }
    }
    __syncthreads();
    const int idx = blockIdx.x * 256 + t;
    float w[NLEV];
    #pragma unroll
    for (int l = 0; l < NLEV; ++l) w[l] = W[l * DD + idx];
    #pragma unroll
    for (int v = 0; v < NLEV; ++v) {
      float s = 0.f;
      #pragma unroll
      for (int l = 0; l < NLEV; ++l) s += c[v * NLEV + l] * w[l];
      weff[v * DD + idx] = f2bf(s);
    }
  } else {
    __shared__ int lc[NLEV];
    const int b = blockIdx.x - DD / 256;   // 0..127
    if (t < NLEV) lc[t] = 0;
    __syncthreads();
    const int gid = b * 256 + t;
    atomicAdd(&lc[clampv(val[gid])], 1);
    perm[gid] = -1;
    if (b < (MROWS_MAX - B_N) / 256) perm[B_N + b * 256 + t] = -1;
    __syncthreads();
    if (t < NLEV) hist[b * NLEV + t] = (u16)lc[t];
  }
}

// ---- K2: deterministic counting-sort scatter (prefix over hist table) ------
__global__ void k2(const int* __restrict__ val, const u16* __restrict__ hist,
                   int* __restrict__ perm, int* __restrict__ starts) {
  __shared__ int h[NHB * NLEV];
  __shared__ int st[NLEV + 1];
  __shared__ int cnt[NLEV];
  __shared__ int lc[NLEV];
  const int t = threadIdx.x, b = blockIdx.x;
  for (int i = t; i < NHB * NLEV; i += 256) h[i] = hist[i];
  if (t < NLEV) lc[t] = 0;
  __syncthreads();
  if (t < NLEV) {
    int run = 0;
    for (int bb = 0; bb < NHB; ++bb) {
      int x = h[bb * NLEV + t];
      h[bb * NLEV + t] = run;
      run += x;
    }
    cnt[t] = run;
  }
  __syncthreads();
  if (t == 0) {
    int s = 0;
    for (int v = 0; v < NLEV; ++v) {
      st[v] = s;
      s += (cnt[v] + TM - 1) & ~(TM - 1);
    }
    st[NLEV] = s;
  }
  __syncthreads();
  const int gid = b * 256 + t;
  const int v = clampv(val[gid]);
  const int pos = atomicAdd(&lc[v], 1);
  perm[st[v] + h[b * NLEV + v] + pos] = gid;
  if (b == 0 && t <= NLEV) starts[t] = st[t];
}

// ---- K3: grouped GEMM, 128x256 tile, dbuf K-loop, row-coalesced epilogue ---
__global__ __launch_bounds__(512, 4) void k3(
    const float* __restrict__ x, const u16* __restrict__ weff,
    const int* __restrict__ perm, const int* __restrict__ starts,
    const float* __restrict__ bias, float* __restrict__ out) {
  __shared__ union SM {
    struct { u16 A[2][TM * BK]; u16 B[2][TN * BK]; } s;   // 48 KB staging
    float c[32 * CSTR];                                    // 33.3 KB epilogue
  } sm;

  const int ct = blockIdx.x, rt = blockIdx.y;
  const int Mpad = starts[NLEV];
  if (rt * TM >= Mpad) return;

  int v = 0;
  #pragma unroll
  for (int i = 1; i < NLEV; ++i) if (rt * TM >= starts[i]) v = i;

  const int tid = threadIdx.x;
  const int lane = tid & 63, wave = tid >> 6;
  const int wm = (wave >> 2) * 64, wn = (wave & 3) * 64;
  const int fm = lane & 15;
  const int cb = lane >> 4;

  // A staging: 4 threads per row, 8 floats (one 16B bf16 chunk) each
  const int ar = tid >> 2;       // 0..127
  const int ah = tid & 3;        // chunk 0..3
  int prow = perm[rt * TM + ar];
  if (prow < 0) prow = 0;
  const float* xrow = x + (size_t)prow * D + ah * 8;
  const int sw = (ar >> 1) & 3;
  const int aslot = ar * BK + ((ah ^ sw) << 3);

  const u16* wb = weff + ((size_t)v * D + ct * TN) * D;
  const int c0i = wave * 64 + lane;            // chunk id = n*4 + slot
  const int c1i = 512 + c0i;
  const int n0 = c0i >> 2, s0 = c0i & 3, kc0 = s0 ^ ((n0 >> 1) & 3);
  const int n1 = c1i >> 2, s1 = c1i & 3, kc1 = s1 ^ ((n1 >> 1) & 3);
  const u16* gb0 = wb + n0 * D + kc0 * 8;
  const u16* gb1 = wb + n1 * D + kc1 * 8;
  const int bdst0 = c0i * 8, bdst1 = c1i * 8;

  f32x4 acc[4][4];
  #pragma unroll
  for (int i = 0; i < 4; ++i)
    #pragma unroll
    for (int j = 0; j < 4; ++j) acc[i][j] = (f32x4){0.f, 0.f, 0.f, 0.f};

  // ---- prologue: stage iter 0, reg-prefetch x for iter 1 ----
  {
    __builtin_amdgcn_global_load_lds(
        (const __attribute__((address_space(1))) void*)gb0,
        (__attribute__((address_space(3))) void*)(sm.s.B[0] + bdst0), 16, 0, 0);
    __builtin_amdgcn_global_load_lds(
        (const __attribute__((address_space(1))) void*)gb1,
        (__attribute__((address_space(3))) void*)(sm.s.B[0] + bdst1), 16, 0, 0);
    const f32x4* xp = (const f32x4*)xrow;
    f32x4 f0 = xp[0], f1 = xp[1];
    u16x8 cc;
    #pragma unroll
    for (int q = 0; q < 4; ++q) { cc[q] = f2bf(f0[q]); cc[4 + q] = f2bf(f1[q]); }
    *(u16x8*)(sm.s.A[0] + aslot) = cc;
  }
  f32x4 cf0, cf1;
  {
    const f32x4* xp = (const f32x4*)(xrow + BK);
    cf0 = xp[0]; cf1 = xp[1];
  }
  __syncthreads();

  int p = 0;
  for (int i = 0; i < NITER; ++i) {
    const bool hn = (i + 1 < NITER);
    if (hn) {
      const int k1o = (i + 1) * BK;
      __builtin_amdgcn_global_load_lds(
          (const __attribute__((address_space(1))) void*)(gb0 + k1o),
          (__attribute__((address_space(3))) void*)(sm.s.B[p ^ 1] + bdst0), 16, 0, 0);
      __builtin_amdgcn_global_load_lds(
          (const __attribute__((address_space(1))) void*)(gb1 + k1o),
          (__attribute__((address_space(3))) void*)(sm.s.B[p ^ 1] + bdst1), 16, 0, 0);
    }
    f32x4 nf0, nf1;
    if (i + 2 < NITER) {
      const f32x4* xp = (const f32x4*)(xrow + (i + 2) * BK);
      nf0 = xp[0]; nf1 = xp[1];
    }
    s16x8 af[4], bf[4];
    #pragma unroll
    for (int t4 = 0; t4 < 4; ++t4) {
      const int m = wm + t4 * 16 + fm;
      af[t4] = *(const s16x8*)(sm.s.A[p] + m * BK + ((cb ^ ((m >> 1) & 3)) << 3));
      const int n = wn + t4 * 16 + fm;
      bf[t4] = *(const s16x8*)(sm.s.B[p] + n * BK + ((cb ^ ((n >> 1) & 3)) << 3));
    }
    #pragma unroll
    for (int tm = 0; tm < 4; ++tm)
      #pragma unroll
      for (int tn = 0; tn < 4; ++tn)
        acc[tm][tn] = __builtin_amdgcn_mfma_f32_16x16x32_bf16(af[tm], bf[tn], acc[tm][tn], 0, 0, 0);
    if (hn) {
      u16x8 cc;
      #pragma unroll
      for (int q = 0; q < 4; ++q) { cc[q] = f2bf(cf0[q]); cc[4 + q] = f2bf(cf1[q]); }
      *(u16x8*)(sm.s.A[p ^ 1] + aslot) = cc;
      cf0 = nf0; cf1 = nf1;
    }
    __syncthreads();
    p ^= 1;
  }

  // ---- epilogue: LDS-transposed, 1KB-contiguous row writes ----
  float bv[4];
  #pragma unroll
  for (int tn = 0; tn < 4; ++tn) bv[tn] = bias[ct * TN + wn + tn * 16 + fm];
  const int row16 = tid >> 4, seg = tid & 15;   // writer role: 16 thr/row
  const int quad = lane >> 4;
  #pragma unroll
  for (int c = 0; c < 4; ++c) {                 // chunk = rows [c*32, c*32+32)
    // dump acc fragments for this chunk's rows into LDS
    #pragma unroll
    for (int tm = 0; tm < 4; ++tm) {
      const int rbase = wm + tm * 16;
      if (rbase >= c * 32 && rbase < c * 32 + 32) {
        const int lr = rbase - c * 32 + quad * 4;
        #pragma unroll
        for (int r = 0; r < 4; ++r)
          #pragma unroll
          for (int tn = 0; tn < 4; ++tn)
            sm.c[(lr + r) * CSTR + wn + tn * 16 + fm] = acc[tm][tn][r] + bv[tn];
      }
    }
    __syncthreads();
    const int p2 = perm[rt * TM + c * 32 + row16];
    if (p2 >= 0) {
      const float* src = sm.c + row16 * CSTR + seg * 16;
      f32x4 v0 = *(const f32x4*)(src + 0);
      f32x4 v1 = *(const f32x4*)(src + 4);
      f32x4 v2 = *(const f32x4*)(src + 8);
      f32x4 v3 = *(const f32x4*)(src + 12);
      float* o = out + (size_t)p2 * D + ct * TN + seg * 16;
      *(f32x4*)(o + 0) = v0;
      *(f32x4*)(o + 4) = v1;
      *(f32x4*)(o + 8) = v2;
      *(f32x4*)(o + 12) = v3;
    }
    __syncthreads();   // protect LDS chunk reuse for next c
  }
}

extern "C" void kernel_launch(void* const* d_in, const int* in_sizes, int n_in,
                              void* d_out, int out_size, void* d_ws, size_t ws_size,
                              hipStream_t stream) {
  const float* x    = (const float*)d_in[0];
  const int*   val  = (const int*)d_in[1];
  const float* W    = (const float*)d_in[2];
  const float* lg   = (const float*)d_in[3];
  const float* attn = (const float*)d_in[4];
  const float* bias = (const float*)d_in[5];
  float* out = (float*)d_out;

  char* ws = (char*)d_ws;
  int* starts = (int*)(ws + 0);          // 11 ints
  u16* hist   = (u16*)(ws + 64);         // 128*10 u16
  int* perm   = (int*)(ws + 2688);       // 34048 ints -> ends 138880
  u16* weff   = (u16*)(ws + 139264);     // 10*512*512 bf16 = 5.24 MB

  k1<<<DD / 256 + NHB, 256, 0, stream>>>(W, lg, attn, val, weff, hist, perm);
  k2<<<NHB, 256, 0, stream>>>(val, hist, perm, starts);
  k3<<<dim3(D / TN, MAX_RT), 512, 0, stream>>>(x, weff, perm, starts, bias, out);
}

// Round 6
// 183.274 us; speedup vs baseline: 1.1272x; 1.1272x over previous
//
#include <hip/hip_runtime.h>

#define B_N 32768
#define D 512
#define DD (D * D)
#define NLEV 10
#define TM 128
#define TN 128
#define BK 32
#define NITER (D / BK)            // 16
#define NHB 128                   // histogram blocks (B_N / 256)
#define MROWS_MAX 34048           // 32768 + 10*128 padding headroom
#define MAX_RT (MROWS_MAX / TM)   // 266
#define NCT (D / TN)              // 4
#define GRID_K3 1088              // ceil(266/8)*8*4 = 34 groups * 32

typedef unsigned short u16;
typedef short s16x8 __attribute__((ext_vector_type(8)));
typedef u16 u16x8 __attribute__((ext_vector_type(8)));
typedef float f32x4 __attribute__((ext_vector_type(4)));

__device__ __forceinline__ u16 f2bf(float f) {
  union { float f; unsigned u; } v; v.f = f;
  unsigned r = v.u + 0x7fffu + ((v.u >> 16) & 1u);  // RNE
  return (u16)(r >> 16);
}
__device__ __forceinline__ int clampv(int v) {
  return v < 0 ? 0 : (v > NLEV - 1 ? NLEV - 1 : v);
}

// ---- K1: weff-build (blocks 0..1023) UNION hist+perm-fill (blocks 1024..1151)
__global__ void k1(const float* __restrict__ W, const float* __restrict__ lg,
                   const float* __restrict__ attn, const int* __restrict__ val,
                   u16* __restrict__ weff, u16* __restrict__ hist,
                   int* __restrict__ perm) {
  const int t = threadIdx.x;
  if (blockIdx.x < DD / 256) {
    __shared__ float c[NLEV * NLEV];
    if (t < NLEV) {
      float g[NLEV], a[NLEV], mx = -1e30f;
      #pragma unroll
      for (int l = 0; l < NLEV; ++l) {
        g[l] = 1.0f / (1.0f + expf(-lg[l]));
        a[l] = attn[t * NLEV + l];
        mx = fmaxf(mx, a[l]);
      }
      float s = 0.f;
      #pragma unroll
      for (int l = 0; l < NLEV; ++l) { a[l] = expf(a[l] - mx); s += a[l]; }
      float inv = 1.0f / s;
      #pragma unroll
      for (int l = 0; l < NLEV; ++l) {
        float cc = 0.3f * a[l] * inv * g[l];
        if (l == t) cc += 0.7f * g[t];
        c[t * NLEV + l] = cc;
      }
    }
    __syncthreads();
    const int idx = blockIdx.x * 256 + t;
    float w[NLEV];
    #pragma unroll
    for (int l = 0; l < NLEV; ++l) w[l] = W[l * DD + idx];
    #pragma unroll
    for (int v = 0; v < NLEV; ++v) {
      float s = 0.f;
      #pragma unroll
      for (int l = 0; l < NLEV; ++l) s += c[v * NLEV + l] * w[l];
      weff[v * DD + idx] = f2bf(s);
    }
  } else {
    __shared__ int lc[NLEV];
    const int b = blockIdx.x - DD / 256;   // 0..127
    if (t < NLEV) lc[t] = 0;
    __syncthreads();
    const int gid = b * 256 + t;
    atomicAdd(&lc[clampv(val[gid])], 1);
    perm[gid] = -1;
    if (b < (MROWS_MAX - B_N) / 256) perm[B_N + b * 256 + t] = -1;
    __syncthreads();
    if (t < NLEV) hist[b * NLEV + t] = (u16)lc[t];
  }
}

// ---- K2: deterministic counting-sort scatter (prefix over hist table) ------
__global__ void k2(const int* __restrict__ val, const u16* __restrict__ hist,
                   int* __restrict__ perm, int* __restrict__ starts) {
  __shared__ int h[NHB * NLEV];
  __shared__ int st[NLEV + 1];
  __shared__ int cnt[NLEV];
  __shared__ int lc[NLEV];
  const int t = threadIdx.x, b = blockIdx.x;
  for (int i = t; i < NHB * NLEV; i += 256) h[i] = hist[i];
  if (t < NLEV) lc[t] = 0;
  __syncthreads();
  if (t < NLEV) {
    int run = 0;
    for (int bb = 0; bb < NHB; ++bb) {
      int x = h[bb * NLEV + t];
      h[bb * NLEV + t] = run;
      run += x;
    }
    cnt[t] = run;
  }
  __syncthreads();
  if (t == 0) {
    int s = 0;
    for (int v = 0; v < NLEV; ++v) {
      st[v] = s;
      s += (cnt[v] + TM - 1) & ~(TM - 1);
    }
    st[NLEV] = s;
  }
  __syncthreads();
  const int gid = b * 256 + t;
  const int v = clampv(val[gid]);
  const int pos = atomicAdd(&lc[v], 1);
  perm[st[v] + h[b * NLEV + v] + pos] = gid;
  if (b == 0 && t <= NLEV) starts[t] = st[t];
}

// ---- K3: grouped GEMM, 128x128 tile, 256 thr, 4 blocks/CU, dbuf K-loop ----
__global__ __launch_bounds__(256, 4) void k3(
    const float* __restrict__ x, const u16* __restrict__ weff,
    const int* __restrict__ perm, const int* __restrict__ starts,
    const float* __restrict__ bias, float* __restrict__ out) {
  __shared__ u16 As[2][TM * BK];   // 2 x 8 KB
  __shared__ u16 Bs[2][TN * BK];   // 2 x 8 KB

  // XCD-aware swizzle: the 4 ct-tiles of one rt sit 8 apart in blockIdx
  // (same XCD under bid%8 dispatch) so per-XCD L2 serves the x re-reads.
  const int bid = blockIdx.x;
  const int rt = (bid >> 5) * 8 + (bid & 7);
  const int ct = (bid >> 3) & 3;
  if (rt >= MAX_RT) return;
  const int Mpad = starts[NLEV];
  if (rt * TM >= Mpad) return;

  int v = 0;
  #pragma unroll
  for (int i = 1; i < NLEV; ++i) if (rt * TM >= starts[i]) v = i;

  const int tid = threadIdx.x;
  const int lane = tid & 63, wave = tid >> 6;
  const int wm = (wave >> 1) * 64, wn = (wave & 1) * 64;
  const int fm = lane & 15;
  const int cb = lane >> 4;

  // A staging: 2 threads per row, 16 floats (two u16x8 chunks) each
  const int ar = tid >> 1;       // 0..127
  const int ah = tid & 1;
  int prow = perm[rt * TM + ar];
  if (prow < 0) prow = 0;
  const float* xrow = x + (size_t)prow * D + ah * 16;
  const int sw = (ar >> 1) & 3;
  const int aslot0 = ar * BK + (((ah * 2 + 0) ^ sw) << 3);
  const int aslot1 = ar * BK + (((ah * 2 + 1) ^ sw) << 3);

  const u16* wb = weff + ((size_t)v * D + ct * TN) * D;
  // B staging: 512 16B chunks (128 rows x 4 slots), source-swizzled
  const int c0i = wave * 64 + lane;            // chunk id = n*4 + slot
  const int c1i = 256 + c0i;
  const int n0 = c0i >> 2, s0 = c0i & 3, kc0 = s0 ^ ((n0 >> 1) & 3);
  const int n1 = c1i >> 2, s1 = c1i & 3, kc1 = s1 ^ ((n1 >> 1) & 3);
  const u16* gb0 = wb + n0 * D + kc0 * 8;
  const u16* gb1 = wb + n1 * D + kc1 * 8;
  const int bdst0 = (wave * 64) * 8;
  const int bdst1 = (256 + wave * 64) * 8;

  f32x4 acc[4][4];
  #pragma unroll
  for (int i = 0; i < 4; ++i)
    #pragma unroll
    for (int j = 0; j < 4; ++j) acc[i][j] = (f32x4){0.f, 0.f, 0.f, 0.f};

  // ---- prologue: stage iter 0 ----
  {
    __builtin_amdgcn_global_load_lds(
        (const __attribute__((address_space(1))) void*)gb0,
        (__attribute__((address_space(3))) void*)(Bs[0] + bdst0), 16, 0, 0);
    __builtin_amdgcn_global_load_lds(
        (const __attribute__((address_space(1))) void*)gb1,
        (__attribute__((address_space(3))) void*)(Bs[0] + bdst1), 16, 0, 0);
    const f32x4* xp = (const f32x4*)xrow;
    f32x4 f0 = xp[0], f1 = xp[1], f2 = xp[2], f3 = xp[3];
    u16x8 c0, c1;
    #pragma unroll
    for (int q = 0; q < 4; ++q) {
      c0[q] = f2bf(f0[q]); c0[4 + q] = f2bf(f1[q]);
      c1[q] = f2bf(f2[q]); c1[4 + q] = f2bf(f3[q]);
    }
    *(u16x8*)(As[0] + aslot0) = c0;
    *(u16x8*)(As[0] + aslot1) = c1;
  }
  __syncthreads();

  int p = 0;
  for (int i = 0; i < NITER; ++i) {
    const bool hn = (i + 1 < NITER);
    // issue B prefetch for iter i+1 into buffer p^1
    if (hn) {
      const int k1o = (i + 1) * BK;
      __builtin_amdgcn_global_load_lds(
          (const __attribute__((address_space(1))) void*)(gb0 + k1o),
          (__attribute__((address_space(3))) void*)(Bs[p ^ 1] + bdst0), 16, 0, 0);
      __builtin_amdgcn_global_load_lds(
          (const __attribute__((address_space(1))) void*)(gb1 + k1o),
          (__attribute__((address_space(3))) void*)(Bs[p ^ 1] + bdst1), 16, 0, 0);
    }
    // issue x load for iter i+1 (consumed after compute below)
    f32x4 f0, f1, f2, f3;
    if (hn) {
      const f32x4* xp = (const f32x4*)(xrow + (i + 1) * BK);
      f0 = xp[0]; f1 = xp[1]; f2 = xp[2]; f3 = xp[3];
    }
    // compute on buffer p (overlaps in-flight loads)
    s16x8 af[4], bf[4];
    #pragma unroll
    for (int t4 = 0; t4 < 4; ++t4) {
      const int m = wm + t4 * 16 + fm;
      af[t4] = *(const s16x8*)(As[p] + m * BK + ((cb ^ ((m >> 1) & 3)) << 3));
      const int n = wn + t4 * 16 + fm;
      bf[t4] = *(const s16x8*)(Bs[p] + n * BK + ((cb ^ ((n >> 1) & 3)) << 3));
    }
    #pragma unroll
    for (int tm = 0; tm < 4; ++tm)
      #pragma unroll
      for (int tn = 0; tn < 4; ++tn)
        acc[tm][tn] = __builtin_amdgcn_mfma_f32_16x16x32_bf16(af[tm], bf[tn], acc[tm][tn], 0, 0, 0);
    // convert + LDS-write the x chunk for iter i+1
    if (hn) {
      u16x8 c0, c1;
      #pragma unroll
      for (int q = 0; q < 4; ++q) {
        c0[q] = f2bf(f0[q]); c0[4 + q] = f2bf(f1[q]);
        c1[q] = f2bf(f2[q]); c1[4 + q] = f2bf(f3[q]);
      }
      *(u16x8*)(As[p ^ 1] + aslot0) = c0;
      *(u16x8*)(As[p ^ 1] + aslot1) = c1;
    }
    __syncthreads();
    p ^= 1;
  }

  // Epilogue (R4-proven): C frag col=lane&15, row=(lane>>4)*4+reg; perm scatter
  float bv[4];
  #pragma unroll
  for (int tn = 0; tn < 4; ++tn) bv[tn] = bias[ct * TN + wn + tn * 16 + fm];
  #pragma unroll
  for (int tm = 0; tm < 4; ++tm) {
    #pragma unroll
    for (int r = 0; r < 4; ++r) {
      const int mrow = wm + tm * 16 + (lane >> 4) * 4 + r;
      const int p2 = perm[rt * TM + mrow];
      if (p2 >= 0) {
        float* o = out + (size_t)p2 * D + ct * TN + wn + fm;
        #pragma unroll
        for (int tn = 0; tn < 4; ++tn)
          o[tn * 16] = acc[tm][tn][r] + bv[tn];
      }
    }
  }
}

extern "C" void kernel_launch(void* const* d_in, const int* in_sizes, int n_in,
                              void* d_out, int out_size, void* d_ws, size_t ws_size,
                              hipStream_t stream) {
  const float* x    = (const float*)d_in[0];
  const int*   val  = (const int*)d_in[1];
  const float* W    = (const float*)d_in[2];
  const float* lg   = (const float*)d_in[3];
  const float* attn = (const float*)d_in[4];
  const float* bias = (const float*)d_in[5];
  float* out = (float*)d_out;

  char* ws = (char*)d_ws;
  int* starts = (int*)(ws + 0);          // 11 ints
  u16* hist   = (u16*)(ws + 64);         // 128*10 u16
  int* perm   = (int*)(ws + 2688);       // 34048 ints -> ends 138880
  u16* weff   = (u16*)(ws + 139264);     // 10*512*512 bf16 = 5.24 MB

  k1<<<DD / 256 + NHB, 256, 0, stream>>>(W, lg, attn, val, weff, hist, perm);
  k2<<<NHB, 256, 0, stream>>>(val, hist, perm, starts);
  k3<<<GRID_K3, 256, 0, stream>>>(x, weff, perm, starts, bias, out);
}